// Round 1
// baseline (108.760 us; speedup 1.0000x reference)
//
#include <hip/hip_runtime.h>

// out[i] = cos(in[i]) — the 2-qubit circuit's <Z0>,<Z1> reduce to cos(r1),cos(r2).
// Memory-bound streaming: 64 MB in + 64 MB out, each touched exactly once.
// dur_us includes two harness poison-fills (~2x41.4 us); our kernel slice is ~24.8 us
// vs a 21.3 us copy-roofline. This revision: ILP-4 — each thread handles 4
// independent float4s at block-stride (coalesced), so 4 global_load_dwordx4
// issue before any cos/store consumes them. No nontemporal, no grid-stride
// (the R3 bundle that regressed).

#define BS 256
#define UNROLL 4

__device__ __forceinline__ float4 cos4(float4 v) {
    float4 r;
    r.x = __cosf(v.x);
    r.y = __cosf(v.y);
    r.z = __cosf(v.z);
    r.w = __cosf(v.w);
    return r;
}

__global__ __launch_bounds__(BS) void qfl_cos_u4(const float4* __restrict__ in,
                                                 float4* __restrict__ out,
                                                 int n4) {
    int i0 = blockIdx.x * (BS * UNROLL) + threadIdx.x;
    if (i0 + (UNROLL - 1) * BS < n4) {
        // Full tile: issue all 4 loads before any consumer so they pipeline.
        float4 a = in[i0];
        float4 b = in[i0 + BS];
        float4 c = in[i0 + 2 * BS];
        float4 d = in[i0 + 3 * BS];
        out[i0]          = cos4(a);   // store(a) overlaps loads b/c/d in flight
        out[i0 + BS]     = cos4(b);
        out[i0 + 2 * BS] = cos4(c);
        out[i0 + 3 * BS] = cos4(d);
    } else {
        // Boundary tile (only the last block can land here).
        #pragma unroll
        for (int u = 0; u < UNROLL; ++u) {
            int i = i0 + u * BS;
            if (i < n4) out[i] = cos4(in[i]);
        }
    }
}

// Scalar tail (n not divisible by 4 — not expected here, but safe).
__global__ void qfl_cos_tail(const float* __restrict__ in,
                             float* __restrict__ out,
                             int start, int n) {
    int i = start + blockIdx.x * blockDim.x + threadIdx.x;
    if (i < n) out[i] = __cosf(in[i]);
}

extern "C" void kernel_launch(void* const* d_in, const int* in_sizes, int n_in,
                              void* d_out, int out_size, void* d_ws, size_t ws_size,
                              hipStream_t stream) {
    const float* in = (const float*)d_in[0];
    float* out = (float*)d_out;
    int n = in_sizes[0];          // 16,777,216 floats (BATCH x 2)
    int n4 = n >> 2;              // 4,194,304 float4 groups

    if (n4 > 0) {
        int perBlock = BS * UNROLL;               // 1024 float4s per block
        int grid = (n4 + perBlock - 1) / perBlock; // 4096 blocks — exact cover
        qfl_cos_u4<<<grid, BS, 0, stream>>>((const float4*)in, (float4*)out, n4);
    }
    int tail_start = n4 << 2;
    int tail = n - tail_start;
    if (tail > 0) {
        qfl_cos_tail<<<1, 64, 0, stream>>>(in, out, tail_start, n);
    }
}

// Round 2
// 106.276 us; speedup vs baseline: 1.0234x; 1.0234x over previous
//
#include <hip/hip_runtime.h>

// out[i] = cos(in[i]) — the 2-qubit circuit's <Z0>,<Z1> reduce to cos(r1),cos(r2)
// (RZZ is a pure phase; probs unchanged; ENTANGLE_STRENGTH=0 anyway).
//
// Memory-bound streaming: 64 MB in + 64 MB out, each touched exactly once.
// dur_us (~107.6) = 2 harness poison-fills (~41.4 us each, 81% HBM peak,
// not ours) + ~25 us kernel slice vs a 21.3 us copy-roofline (6.29 TB/s, m13).
//
// Attempt history on the ~3.5 us residual — all failed, all reverted:
//   R3: nontemporal load/store + grid-stride  → 108→114 us (REGRESSED)
//   R4: ILP-4 (4 independent float4/thread)   → 107.6→108.8 us (REGRESSED)
//       post-mortem: at 8 VGPR the kernel runs full occupancy (8 waves/SIMD);
//       TLP already saturates memory-level parallelism, so per-thread ILP
//       bought nothing and the 4x smaller grid + tile branch cost ~1 us.
// Conclusion: one float4/thread, exact cover, plain cached dwordx4 loads/
// stores IS the measured floor for this mixed 1R+1W stream. ROOFLINE.

__global__ __launch_bounds__(256) void qfl_cos_kernel(const float4* __restrict__ in,
                                                      float4* __restrict__ out,
                                                      int n4) {
    int i = blockIdx.x * blockDim.x + threadIdx.x;
    if (i < n4) {
        float4 v = in[i];
        float4 r;
        r.x = __cosf(v.x);
        r.y = __cosf(v.y);
        r.z = __cosf(v.z);
        r.w = __cosf(v.w);
        out[i] = r;
    }
}

// Scalar tail (n not divisible by 4 — not expected here, but safe).
__global__ void qfl_cos_tail(const float* __restrict__ in,
                             float* __restrict__ out,
                             int start, int n) {
    int i = start + blockIdx.x * blockDim.x + threadIdx.x;
    if (i < n) out[i] = __cosf(in[i]);
}

extern "C" void kernel_launch(void* const* d_in, const int* in_sizes, int n_in,
                              void* d_out, int out_size, void* d_ws, size_t ws_size,
                              hipStream_t stream) {
    const float* in = (const float*)d_in[0];
    float* out = (float*)d_out;
    int n = in_sizes[0];          // 16,777,216 floats (BATCH x 2)
    int n4 = n >> 2;              // 4,194,304 float4 groups

    if (n4 > 0) {
        int block = 256;
        int grid = (n4 + block - 1) / block;
        qfl_cos_kernel<<<grid, block, 0, stream>>>((const float4*)in, (float4*)out, n4);
    }
    int tail_start = n4 << 2;
    int tail = n - tail_start;
    if (tail > 0) {
        qfl_cos_tail<<<1, 64, 0, stream>>>(in, out, tail_start, n);
    }
}